// Round 1
// baseline (412.642 us; speedup 1.0000x reference)
//
#include <hip/hip_runtime.h>
#include <cstdint>
#include <cstddef>

// Problem constants (match reference)
#define Bb 64
#define Ss 197
#define Dd 768
#define Pp 196
// M = Bb*Pp = 12544 sampled rows; GEMM: out = gatherA(x) @ Wv + wsum*bv
// Grid exactness: 12544 = 98*128, 768 = 6*128 = 48*16 -> no bounds checks.

constexpr int BM = 128, BN = 128, BK = 16;

struct alignas(16) F4 { float v[4]; };

__device__ __forceinline__ int mod_s(int v) {
    int r = v % Ss;
    return (r < 0) ? r + Ss : r;   // Python/JAX % semantics (non-negative)
}

__global__ __launch_bounds__(256) void gsa_fused_gemm(
    const float* __restrict__ x,        // (B,S,D)
    const int*   __restrict__ img_ids,  // (B,)
    const float* __restrict__ Wv,       // (D,D) row-major
    const float* __restrict__ bv,       // (D,)
    const float* __restrict__ avgs,     // (N_IMGS,2,P)
    const float* __restrict__ stds,     // (N_IMGS,2,P)
    const float* __restrict__ noise,    // (B,2,P)
    float* __restrict__ out)            // (B,S,D)
{
    __shared__ float As[BK][BM];      // [k][m]
    __shared__ float Bs[BK][BN];      // [k][n]
    __shared__ float wsums[BM];

    const int t  = threadIdx.x;
    const int m0 = blockIdx.x * BM;
    const int n0 = blockIdx.y * BN;

    // ---- A staging assignment: thread stages row r = t>>1, k-half = t&1 ----
    const int r     = t >> 1;
    const int khalf = t & 1;

    float w0, w1, w2, w3;
    const float* srcA0;
    const float* srcA1;
    const float* srcA2;
    const float* srcA3;
    {
        const int m  = m0 + r;
        const int b  = m / Pp;
        const int p  = m - b * Pp;
        const int id = img_ids[b];
        const float a0 = avgs [((size_t)id * 2    ) * Pp + p];
        const float a1 = avgs [((size_t)id * 2 + 1) * Pp + p];
        const float s0 = stds [((size_t)id * 2    ) * Pp + p];
        const float s1 = stds [((size_t)id * 2 + 1) * Pp + p];
        const float nx = noise[((size_t)b  * 2    ) * Pp + p];
        const float ny = noise[((size_t)b  * 2 + 1) * Pp + p];

        const float kx = (nx - a0) / s0;
        const float ky = (ny - a1) / s1;
        const float cx = ceilf(kx),  fx = floorf(kx);
        const float cy = ceilf(ky),  fy = floorf(ky);
        const float dcx = 1.0f - fabsf(cx - kx);
        const float dfx = 1.0f - fabsf(fx - kx);
        const float dcy = 1.0f - fabsf(cy - ky);
        const float dfy = 1.0f - fabsf(fy - ky);
        w0 = dcx * dcy;   // (ceil x, ceil y)  == w11
        w1 = dfx * dcy;   // (floor x, ceil y) == w21
        w2 = dcx * dfy;   // (ceil x, floor y) == w12
        w3 = dfx * dfy;   // (floor x, floor y)== w22
        const int i0 = mod_s((int)(14.0f * cy + cx));
        const int i1 = mod_s((int)(14.0f * cy + fx));
        const int i2 = mod_s((int)(14.0f * fy + cx));
        const int i3 = mod_s((int)(14.0f * fy + fx));
        const size_t xb = (size_t)b * Ss;
        const int ko = khalf * 8;
        srcA0 = x + (xb + i0) * Dd + ko;
        srcA1 = x + (xb + i1) * Dd + ko;
        srcA2 = x + (xb + i2) * Dd + ko;
        srcA3 = x + (xb + i3) * Dd + ko;
        if (khalf == 0) wsums[r] = w0 + w1 + w2 + w3;
    }

    // ---- B staging assignment: thread t loads Wv[kt+bkk][n0+bc(+64)] ----
    const int bkk = t >> 4;          // 0..15
    const int bc  = (t & 15) * 4;    // 0,4,...,60  (2-way bank aliasing: free)

    // ---- compute assignment: 8x8 per thread ----
    const int tx = t & 15;           // cols: tx*4..+3 and 64+tx*4..+3
    const int ty = t >> 4;           // rows: ty*8..+7

    float acc[8][8];
    #pragma unroll
    for (int i = 0; i < 8; ++i)
        #pragma unroll
        for (int j = 0; j < 8; ++j) acc[i][j] = 0.0f;

    for (int kt = 0; kt < Dd; kt += BK) {
        // global loads (registers only; no LDS touch before barrier)
        F4 la00 = *reinterpret_cast<const F4*>(srcA0 + kt);
        F4 la01 = *reinterpret_cast<const F4*>(srcA0 + kt + 4);
        F4 la10 = *reinterpret_cast<const F4*>(srcA1 + kt);
        F4 la11 = *reinterpret_cast<const F4*>(srcA1 + kt + 4);
        F4 la20 = *reinterpret_cast<const F4*>(srcA2 + kt);
        F4 la21 = *reinterpret_cast<const F4*>(srcA2 + kt + 4);
        F4 la30 = *reinterpret_cast<const F4*>(srcA3 + kt);
        F4 la31 = *reinterpret_cast<const F4*>(srcA3 + kt + 4);
        const float* wrow = Wv + (size_t)(kt + bkk) * Dd + n0 + bc;
        F4 lb0 = *reinterpret_cast<const F4*>(wrow);
        F4 lb1 = *reinterpret_cast<const F4*>(wrow + 64);

        float ua[8];
        #pragma unroll
        for (int q = 0; q < 4; ++q) {
            ua[q]     = w0*la00.v[q] + w1*la10.v[q] + w2*la20.v[q] + w3*la30.v[q];
            ua[q + 4] = w0*la01.v[q] + w1*la11.v[q] + w2*la21.v[q] + w3*la31.v[q];
        }

        __syncthreads();   // previous iter's LDS reads done
        #pragma unroll
        for (int q = 0; q < 8; ++q) As[khalf * 8 + q][r] = ua[q];
        *reinterpret_cast<F4*>(&Bs[bkk][bc])      = lb0;
        *reinterpret_cast<F4*>(&Bs[bkk][bc + 64]) = lb1;
        __syncthreads();

        #pragma unroll
        for (int kk = 0; kk < BK; ++kk) {
            F4 av0 = *reinterpret_cast<const F4*>(&As[kk][ty * 8]);
            F4 av1 = *reinterpret_cast<const F4*>(&As[kk][ty * 8 + 4]);
            F4 bb0 = *reinterpret_cast<const F4*>(&Bs[kk][tx * 4]);
            F4 bb1 = *reinterpret_cast<const F4*>(&Bs[kk][64 + tx * 4]);
            #pragma unroll
            for (int i = 0; i < 4; ++i) {
                #pragma unroll
                for (int j = 0; j < 4; ++j) {
                    acc[i][j]         += av0.v[i] * bb0.v[j];
                    acc[i][j + 4]     += av0.v[i] * bb1.v[j];
                    acc[i + 4][j]     += av1.v[i] * bb0.v[j];
                    acc[i + 4][j + 4] += av1.v[i] * bb1.v[j];
                }
            }
        }
    }

    // ---- epilogue: + wsum*bv, write out rows 1+p ----
    const float* bvp = bv + n0 + tx * 4;
    F4 bvv0 = *reinterpret_cast<const F4*>(bvp);
    F4 bvv1 = *reinterpret_cast<const F4*>(bvp + 64);
    #pragma unroll
    for (int i = 0; i < 8; ++i) {
        const int m = m0 + ty * 8 + i;
        const int b = m / Pp;
        const int p = m - b * Pp;
        const float ws = wsums[ty * 8 + i];
        float* orow = out + ((size_t)b * Ss + 1 + p) * Dd + n0;
        F4 o0, o1;
        #pragma unroll
        for (int j = 0; j < 4; ++j) {
            o0.v[j] = acc[i][j]     + ws * bvv0.v[j];
            o1.v[j] = acc[i][j + 4] + ws * bvv1.v[j];
        }
        *reinterpret_cast<F4*>(&orow[tx * 4])      = o0;
        *reinterpret_cast<F4*>(&orow[64 + tx * 4]) = o1;
    }
}

// class-token rows: out[b,0,:] = 1.0  (attn==1 since softmax over singleton axis)
__global__ __launch_bounds__(256) void gsa_fill_cls(float* __restrict__ out) {
    const int idx = blockIdx.x * 256 + threadIdx.x;   // B*D = 49152
    if (idx < Bb * Dd) {
        const int b = idx / Dd;
        const int d = idx - b * Dd;
        out[(size_t)b * Ss * Dd + d] = 1.0f;
    }
}

extern "C" void kernel_launch(void* const* d_in, const int* in_sizes, int n_in,
                              void* d_out, int out_size, void* d_ws, size_t ws_size,
                              hipStream_t stream) {
    // setup_inputs order: x, img_ids, mask, Wq, bq, Wk, bk, Wv, bv, avgs, std_devs, noise
    const float* x       = (const float*)d_in[0];
    const int*   img_ids = (const int*)  d_in[1];
    // d_in[2] mask: unused
    const float* Wv      = (const float*)d_in[7];
    const float* bv      = (const float*)d_in[8];
    const float* avgs    = (const float*)d_in[9];
    const float* stds    = (const float*)d_in[10];
    const float* noise   = (const float*)d_in[11];
    float* out = (float*)d_out;

    gsa_fill_cls<<<(Bb * Dd + 255) / 256, 256, 0, stream>>>(out);

    dim3 grid((Bb * Pp) / BM, Dd / BN);   // 98 x 6
    gsa_fused_gemm<<<grid, 256, 0, stream>>>(x, img_ids, Wv, bv, avgs, stds, noise, out);
}

// Round 2
// 272.410 us; speedup vs baseline: 1.5148x; 1.5148x over previous
//
#include <hip/hip_runtime.h>
#include <cstdint>
#include <cstddef>

// Problem constants (match reference)
#define Bb 64
#define Ss 197
#define Dd 768
#define Pp 196
// Dead-code analysis: softmax over singleton axis => attn == 1 => out = sampled_v.
// out[b,0,:] = 1; out[b,1+p,:] = sum_j w_j * v[b,i_j,:],  v = x@Wv + bv
// Gather commutes with GEMM: out_row = (sum_j w_j x[b,i_j,:]) @ Wv + (sum w_j) bv.
// M = 12544 = 98*128, N = K = 768.

typedef short bf16x8 __attribute__((ext_vector_type(8)));
typedef float f32x4  __attribute__((ext_vector_type(4)));
struct alignas(16) F4 { float v[4]; };

__device__ __forceinline__ int mod_s(int v) {
    int r = v % Ss;
    return (r < 0) ? r + Ss : r;   // Python/JAX % semantics
}

__device__ __forceinline__ unsigned short f2bf(float f) {
    union { float f; unsigned u; } v; v.f = f;
    unsigned r = (v.u + 0x7FFFu + ((v.u >> 16) & 1u)) >> 16;  // RNE
    return (unsigned short)r;
}

// ---------------- WvT: Wv (K x N, fp32) -> WvT (N x K, bf16) in ws ----------------
__global__ __launch_bounds__(256) void wv_transpose(
    const float* __restrict__ Wv, unsigned short* __restrict__ WvT)
{
    const int u = blockIdx.x * 256 + threadIdx.x;   // 73728 threads
    const int o = u * 8;                            // flat (n*768 + k), k%8==0
    const int n = o / Dd;
    const int k = o - n * Dd;
    bf16x8 tv;
    #pragma unroll
    for (int j = 0; j < 8; ++j) tv[j] = (short)f2bf(Wv[(size_t)(k + j) * Dd + n]);
    *reinterpret_cast<bf16x8*>(WvT + o) = tv;   // coalesced 16B stores
}

// ---------------- class-token rows: out[b,0,:] = 1.0 ----------------
__global__ __launch_bounds__(256) void gsa_fill_cls(float* __restrict__ out) {
    const int idx = blockIdx.x * 256 + threadIdx.x;   // B*D = 49152
    if (idx < Bb * Dd) {
        const int b = idx / Dd;
        const int d = idx - b * Dd;
        out[(size_t)b * Ss * Dd + d] = 1.0f;
    }
}

// ---------------- fused gather + bf16 MFMA GEMM ----------------
// Tile 128x128, BK=32. 256 threads = 4 waves; wave = 64x64 subtile = 4x4 MFMAs.
__global__ __launch_bounds__(256, 2) void gsa_mfma(
    const float* __restrict__ x,
    const int*   __restrict__ img_ids,
    const unsigned short* __restrict__ WvT,   // (N,K) bf16
    const float* __restrict__ bv,
    const float* __restrict__ avgs,
    const float* __restrict__ stds,
    const float* __restrict__ noise,
    float* __restrict__ out)
{
    __shared__ short As[128][40];   // [m][k], pad 32->40 (b128 reads: 8 acc/bank)
    __shared__ short Bs[128][40];   // [n][k]
    __shared__ float wsums[128];

    const int t  = threadIdx.x;
    const int m0 = blockIdx.x * 128;
    const int n0 = blockIdx.y * 128;

    // staging assignment: row r (0..127), k-half kh (0/1) -> 16 k-elements
    const int r  = t >> 1;
    const int kh = t & 1;
    const int ko = kh * 16;

    // ---- gather setup (weights + 4 source-row pointers), all fp32-exact ----
    float w0, w1, w2, w3;
    const float *sA0, *sA1, *sA2, *sA3;
    {
        const int m  = m0 + r;
        const int b  = m / Pp;
        const int p  = m - b * Pp;
        const int id = img_ids[b];
        const float a0 = avgs [((size_t)id * 2    ) * Pp + p];
        const float a1 = avgs [((size_t)id * 2 + 1) * Pp + p];
        const float s0 = stds [((size_t)id * 2    ) * Pp + p];
        const float s1 = stds [((size_t)id * 2 + 1) * Pp + p];
        const float nx = noise[((size_t)b  * 2    ) * Pp + p];
        const float ny = noise[((size_t)b  * 2 + 1) * Pp + p];
        const float kx = (nx - a0) / s0;
        const float ky = (ny - a1) / s1;
        const float cx = ceilf(kx),  fx = floorf(kx);
        const float cy = ceilf(ky),  fy = floorf(ky);
        const float dcx = 1.0f - fabsf(cx - kx);
        const float dfx = 1.0f - fabsf(fx - kx);
        const float dcy = 1.0f - fabsf(cy - ky);
        const float dfy = 1.0f - fabsf(fy - ky);
        w0 = dcx * dcy;  w1 = dfx * dcy;  w2 = dcx * dfy;  w3 = dfx * dfy;
        const int i0 = mod_s((int)(14.0f * cy + cx));
        const int i1 = mod_s((int)(14.0f * cy + fx));
        const int i2 = mod_s((int)(14.0f * fy + cx));
        const int i3 = mod_s((int)(14.0f * fy + fx));
        const size_t xb = (size_t)b * Ss;
        sA0 = x + (xb + i0) * Dd + ko;
        sA1 = x + (xb + i1) * Dd + ko;
        sA2 = x + (xb + i2) * Dd + ko;
        sA3 = x + (xb + i3) * Dd + ko;
        if (kh == 0) wsums[r] = w0 + w1 + w2 + w3;
    }
    const unsigned short* srcB = WvT + (size_t)(n0 + r) * Dd + ko;

    // ---- MFMA fragment assignment ----
    const int lane = t & 63;
    const int wv   = t >> 6;
    const int col  = lane & 15;
    const int quad = lane >> 4;
    const int wm   = (wv & 1) * 64;
    const int wn   = (wv >> 1) * 64;

    const short* aptr[4];
    const short* bptr[4];
    #pragma unroll
    for (int mi = 0; mi < 4; ++mi) aptr[mi] = &As[wm + mi * 16 + col][quad * 8];
    #pragma unroll
    for (int ni = 0; ni < 4; ++ni) bptr[ni] = &Bs[wn + ni * 16 + col][quad * 8];

    f32x4 acc[4][4];
    #pragma unroll
    for (int i = 0; i < 4; ++i)
        #pragma unroll
        for (int j = 0; j < 4; ++j) acc[i][j] = (f32x4)0.0f;

    #pragma unroll 1
    for (int kt = 0; kt < Dd; kt += 32) {
        // global loads (registers only before barrier)
        F4 l0[4], l1[4], l2[4], l3[4];
        #pragma unroll
        for (int c = 0; c < 4; ++c) {
            l0[c] = *reinterpret_cast<const F4*>(sA0 + kt + c * 4);
            l1[c] = *reinterpret_cast<const F4*>(sA1 + kt + c * 4);
            l2[c] = *reinterpret_cast<const F4*>(sA2 + kt + c * 4);
            l3[c] = *reinterpret_cast<const F4*>(sA3 + kt + c * 4);
        }
        bf16x8 b0 = *reinterpret_cast<const bf16x8*>(srcB + kt);
        bf16x8 b1 = *reinterpret_cast<const bf16x8*>(srcB + kt + 8);

        bf16x8 ua0, ua1;
        #pragma unroll
        for (int e = 0; e < 8; ++e) {
            const int c = e >> 2, q = e & 3;
            ua0[e] = (short)f2bf(w0*l0[c].v[q] + w1*l1[c].v[q] + w2*l2[c].v[q] + w3*l3[c].v[q]);
        }
        #pragma unroll
        for (int e = 0; e < 8; ++e) {
            const int c = (e + 8) >> 2, q = e & 3;
            ua1[e] = (short)f2bf(w0*l0[c].v[q] + w1*l1[c].v[q] + w2*l2[c].v[q] + w3*l3[c].v[q]);
        }

        __syncthreads();   // prior iter's frag reads done
        *reinterpret_cast<bf16x8*>(&As[r][ko])     = ua0;
        *reinterpret_cast<bf16x8*>(&As[r][ko + 8]) = ua1;
        *reinterpret_cast<bf16x8*>(&Bs[r][ko])     = b0;
        *reinterpret_cast<bf16x8*>(&Bs[r][ko + 8]) = b1;
        __syncthreads();

        bf16x8 aF[4], bF[4];
        #pragma unroll
        for (int mi = 0; mi < 4; ++mi) aF[mi] = *reinterpret_cast<const bf16x8*>(aptr[mi]);
        #pragma unroll
        for (int ni = 0; ni < 4; ++ni) bF[ni] = *reinterpret_cast<const bf16x8*>(bptr[ni]);
        #pragma unroll
        for (int mi = 0; mi < 4; ++mi)
            #pragma unroll
            for (int ni = 0; ni < 4; ++ni)
                acc[mi][ni] = __builtin_amdgcn_mfma_f32_16x16x32_bf16(
                    aF[mi], bF[ni], acc[mi][ni], 0, 0, 0);
    }

    // ---- epilogue: + wsum*bv, scatter to out rows (skip cls row) ----
    float bvv[4];
    #pragma unroll
    for (int ni = 0; ni < 4; ++ni) bvv[ni] = bv[n0 + wn + ni * 16 + col];

    #pragma unroll
    for (int mi = 0; mi < 4; ++mi) {
        #pragma unroll
        for (int rg = 0; rg < 4; ++rg) {
            const int ml = wm + mi * 16 + quad * 4 + rg;   // C/D row = quad*4+reg
            const int mg = m0 + ml;
            const int b  = mg / Pp;
            const float wsv = wsums[ml];
            float* orow = out + ((size_t)(mg + b + 1)) * Dd;  // b*197 + 1 + p
            #pragma unroll
            for (int ni = 0; ni < 4; ++ni)
                orow[n0 + wn + ni * 16 + col] = acc[mi][ni][rg] + wsv * bvv[ni];
        }
    }
}

// ================= fallback fp32 path (round-1 kernel, used if ws too small) =================
constexpr int BM = 128, BN = 128, BK = 16;

__global__ __launch_bounds__(256) void gsa_fused_gemm(
    const float* __restrict__ x, const int* __restrict__ img_ids,
    const float* __restrict__ Wv, const float* __restrict__ bv,
    const float* __restrict__ avgs, const float* __restrict__ stds,
    const float* __restrict__ noise, float* __restrict__ out)
{
    __shared__ float As[BK][BM];
    __shared__ float Bs[BK][BN];
    __shared__ float wsums[BM];
    const int t  = threadIdx.x;
    const int m0 = blockIdx.x * BM;
    const int n0 = blockIdx.y * BN;
    const int r = t >> 1, khalf = t & 1;
    float w0, w1, w2, w3;
    const float *srcA0, *srcA1, *srcA2, *srcA3;
    {
        const int m = m0 + r, b = m / Pp, p = m - b * Pp;
        const int id = img_ids[b];
        const float a0 = avgs[((size_t)id*2)*Pp+p], a1 = avgs[((size_t)id*2+1)*Pp+p];
        const float s0 = stds[((size_t)id*2)*Pp+p], s1 = stds[((size_t)id*2+1)*Pp+p];
        const float nx = noise[((size_t)b*2)*Pp+p], ny = noise[((size_t)b*2+1)*Pp+p];
        const float kx = (nx-a0)/s0, ky = (ny-a1)/s1;
        const float cx = ceilf(kx), fx = floorf(kx), cy = ceilf(ky), fy = floorf(ky);
        const float dcx = 1.0f-fabsf(cx-kx), dfx = 1.0f-fabsf(fx-kx);
        const float dcy = 1.0f-fabsf(cy-ky), dfy = 1.0f-fabsf(fy-ky);
        w0 = dcx*dcy; w1 = dfx*dcy; w2 = dcx*dfy; w3 = dfx*dfy;
        const int i0 = mod_s((int)(14.0f*cy+cx)), i1 = mod_s((int)(14.0f*cy+fx));
        const int i2 = mod_s((int)(14.0f*fy+cx)), i3 = mod_s((int)(14.0f*fy+fx));
        const size_t xb = (size_t)b * Ss;
        const int kko = khalf * 8;
        srcA0 = x + (xb+i0)*Dd + kko; srcA1 = x + (xb+i1)*Dd + kko;
        srcA2 = x + (xb+i2)*Dd + kko; srcA3 = x + (xb+i3)*Dd + kko;
        if (khalf == 0) wsums[r] = w0+w1+w2+w3;
    }
    const int bkk = t >> 4, bc = (t & 15) * 4;
    const int tx = t & 15, ty = t >> 4;
    float acc[8][8];
    #pragma unroll
    for (int i = 0; i < 8; ++i)
        #pragma unroll
        for (int j = 0; j < 8; ++j) acc[i][j] = 0.0f;
    for (int kt = 0; kt < Dd; kt += BK) {
        F4 la00 = *reinterpret_cast<const F4*>(srcA0+kt),   la01 = *reinterpret_cast<const F4*>(srcA0+kt+4);
        F4 la10 = *reinterpret_cast<const F4*>(srcA1+kt),   la11 = *reinterpret_cast<const F4*>(srcA1+kt+4);
        F4 la20 = *reinterpret_cast<const F4*>(srcA2+kt),   la21 = *reinterpret_cast<const F4*>(srcA2+kt+4);
        F4 la30 = *reinterpret_cast<const F4*>(srcA3+kt),   la31 = *reinterpret_cast<const F4*>(srcA3+kt+4);
        const float* wrow = Wv + (size_t)(kt+bkk)*Dd + n0 + bc;
        F4 lb0 = *reinterpret_cast<const F4*>(wrow), lb1 = *reinterpret_cast<const F4*>(wrow+64);
        float ua[8];
        #pragma unroll
        for (int q = 0; q < 4; ++q) {
            ua[q]   = w0*la00.v[q]+w1*la10.v[q]+w2*la20.v[q]+w3*la30.v[q];
            ua[q+4] = w0*la01.v[q]+w1*la11.v[q]+w2*la21.v[q]+w3*la31.v[q];
        }
        __syncthreads();
        #pragma unroll
        for (int q = 0; q < 8; ++q) As[khalf*8+q][r] = ua[q];
        *reinterpret_cast<F4*>(&Bs[bkk][bc])    = lb0;
        *reinterpret_cast<F4*>(&Bs[bkk][bc+64]) = lb1;
        __syncthreads();
        #pragma unroll
        for (int kk = 0; kk < BK; ++kk) {
            F4 av0 = *reinterpret_cast<const F4*>(&As[kk][ty*8]);
            F4 av1 = *reinterpret_cast<const F4*>(&As[kk][ty*8+4]);
            F4 bb0 = *reinterpret_cast<const F4*>(&Bs[kk][tx*4]);
            F4 bb1 = *reinterpret_cast<const F4*>(&Bs[kk][64+tx*4]);
            #pragma unroll
            for (int i = 0; i < 4; ++i)
                #pragma unroll
                for (int j = 0; j < 4; ++j) {
                    acc[i][j]     += av0.v[i]*bb0.v[j];
                    acc[i][j+4]   += av0.v[i]*bb1.v[j];
                    acc[i+4][j]   += av1.v[i]*bb0.v[j];
                    acc[i+4][j+4] += av1.v[i]*bb1.v[j];
                }
        }
    }
    const float* bvp = bv + n0 + tx*4;
    F4 bvv0 = *reinterpret_cast<const F4*>(bvp), bvv1 = *reinterpret_cast<const F4*>(bvp+64);
    #pragma unroll
    for (int i = 0; i < 8; ++i) {
        const int m = m0 + ty*8 + i, b = m / Pp, p = m - b*Pp;
        const float ws = wsums[ty*8+i];
        float* orow = out + ((size_t)b*Ss + 1 + p)*Dd + n0;
        F4 o0, o1;
        #pragma unroll
        for (int j = 0; j < 4; ++j) {
            o0.v[j] = acc[i][j]   + ws*bvv0.v[j];
            o1.v[j] = acc[i][j+4] + ws*bvv1.v[j];
        }
        *reinterpret_cast<F4*>(&orow[tx*4])    = o0;
        *reinterpret_cast<F4*>(&orow[64+tx*4]) = o1;
    }
}

extern "C" void kernel_launch(void* const* d_in, const int* in_sizes, int n_in,
                              void* d_out, int out_size, void* d_ws, size_t ws_size,
                              hipStream_t stream) {
    // order: x, img_ids, mask, Wq, bq, Wk, bk, Wv, bv, avgs, std_devs, noise
    const float* x       = (const float*)d_in[0];
    const int*   img_ids = (const int*)  d_in[1];
    const float* Wv      = (const float*)d_in[7];
    const float* bv      = (const float*)d_in[8];
    const float* avgs    = (const float*)d_in[9];
    const float* stds    = (const float*)d_in[10];
    const float* noise   = (const float*)d_in[11];
    float* out = (float*)d_out;

    gsa_fill_cls<<<(Bb * Dd + 255) / 256, 256, 0, stream>>>(out);

    const size_t wvt_bytes = (size_t)Dd * Dd * sizeof(unsigned short);  // 1.18 MB
    if (ws_size >= wvt_bytes && d_ws != nullptr) {
        unsigned short* WvT = (unsigned short*)d_ws;
        wv_transpose<<<(Dd * Dd / 8) / 256, 256, 0, stream>>>(Wv, WvT);
        dim3 grid((Bb * Pp) / 128, Dd / 128);   // 98 x 6
        gsa_mfma<<<grid, 256, 0, stream>>>(x, img_ids, WvT, bv, avgs, stds, noise, out);
    } else {
        dim3 grid((Bb * Pp) / BM, Dd / BN);
        gsa_fused_gemm<<<grid, 256, 0, stream>>>(x, img_ids, Wv, bv, avgs, stds, noise, out);
    }
}

// Round 3
// 257.908 us; speedup vs baseline: 1.6000x; 1.0562x over previous
//
#include <hip/hip_runtime.h>
#include <cstdint>
#include <cstddef>

// Problem constants
#define Bb 64
#define Ss 197
#define Dd 768
#define Pp 196
// Dead code: softmax over singleton axis -> attn==1 -> out = sampled_v.
// out[b,0,:]=1 ; out[b,1+p,:] = (sum_j w_j x[b,i_j,:]) @ Wv + (sum_j w_j) bv
// M = 12544 = 98*128, N = K = 768.

typedef short bf16x8 __attribute__((ext_vector_type(8)));
typedef short bf16x4 __attribute__((ext_vector_type(4)));
typedef float f32x4  __attribute__((ext_vector_type(4)));
struct alignas(16) F4 { float v[4]; };

__device__ __forceinline__ int mod_s(int v) {
    int r = v % Ss;
    return (r < 0) ? r + Ss : r;   // Python/JAX % semantics
}

__device__ __forceinline__ unsigned short f2bf(float f) {
    union { float f; unsigned u; } v; v.f = f;
    unsigned r = (v.u + 0x7FFFu + ((v.u >> 16) & 1u)) >> 16;  // RNE
    return (unsigned short)r;
}

struct GParams {
    float w0, w1, w2, w3;
    int i0, i1, i2, i3;
};

__device__ __forceinline__ GParams gather_params(
    const int* img_ids, const float* avgs, const float* stds,
    const float* noise, int b, int p)
{
    const int id = img_ids[b];
    const float a0 = avgs [((size_t)id * 2    ) * Pp + p];
    const float a1 = avgs [((size_t)id * 2 + 1) * Pp + p];
    const float s0 = stds [((size_t)id * 2    ) * Pp + p];
    const float s1 = stds [((size_t)id * 2 + 1) * Pp + p];
    const float nx = noise[((size_t)b  * 2    ) * Pp + p];
    const float ny = noise[((size_t)b  * 2 + 1) * Pp + p];
    const float kx = (nx - a0) / s0;
    const float ky = (ny - a1) / s1;
    const float cx = ceilf(kx),  fx = floorf(kx);
    const float cy = ceilf(ky),  fy = floorf(ky);
    const float dcx = 1.0f - fabsf(cx - kx);
    const float dfx = 1.0f - fabsf(fx - kx);
    const float dcy = 1.0f - fabsf(cy - ky);
    const float dfy = 1.0f - fabsf(fy - ky);
    GParams g;
    g.w0 = dcx * dcy;  g.w1 = dfx * dcy;  g.w2 = dcx * dfy;  g.w3 = dfx * dfy;
    g.i0 = mod_s((int)(14.0f * cy + cx));
    g.i1 = mod_s((int)(14.0f * cy + fx));
    g.i2 = mod_s((int)(14.0f * fy + cx));
    g.i3 = mod_s((int)(14.0f * fy + fx));
    return g;
}

// ================= prep: gather->Ag (bf16), Wv->WvT (bf16), cls rows =================
// blocks [0,3136): gather, 4 rows/block (1 wave each)
// blocks [3136,3280): Wv 64x64 LDS-tiled transpose+convert (12x12 tiles)
// blocks [3280,3472): out[b,0,:] = 1
#define GATHER_BLKS 3136
#define TRANS_BLKS  144
#define CLS_BLKS    192

__global__ __launch_bounds__(256) void gsa_prep(
    const float* __restrict__ x,
    const int*   __restrict__ img_ids,
    const float* __restrict__ Wv,
    const float* __restrict__ avgs,
    const float* __restrict__ stds,
    const float* __restrict__ noise,
    unsigned short* __restrict__ Ag,    // (M,K) bf16
    unsigned short* __restrict__ WvT,   // (N,K) bf16
    float* __restrict__ wsB,            // (M,)
    float* __restrict__ out)
{
    __shared__ short T[64][66];   // transpose tile, stride 33 words: conflict-free
    const int t   = threadIdx.x;
    const int blk = blockIdx.x;

    if (blk < GATHER_BLKS) {
        const int lane = t & 63;
        const int w    = t >> 6;
        const int m    = blk * 4 + w;
        const int b    = m / Pp;
        const int p    = m - b * Pp;
        GParams g = gather_params(img_ids, avgs, stds, noise, b, p);
        const size_t xb = (size_t)b * Ss;
        const float* r0 = x + (xb + g.i0) * Dd;
        const float* r1 = x + (xb + g.i1) * Dd;
        const float* r2 = x + (xb + g.i2) * Dd;
        const float* r3 = x + (xb + g.i3) * Dd;
        unsigned short* dst = Ag + (size_t)m * Dd;
        #pragma unroll
        for (int c = 0; c < 3; ++c) {
            const int k = c * 256 + lane * 4;
            F4 v0 = *reinterpret_cast<const F4*>(r0 + k);
            F4 v1 = *reinterpret_cast<const F4*>(r1 + k);
            F4 v2 = *reinterpret_cast<const F4*>(r2 + k);
            F4 v3 = *reinterpret_cast<const F4*>(r3 + k);
            bf16x4 o;
            #pragma unroll
            for (int q = 0; q < 4; ++q)
                o[q] = (short)f2bf(g.w0*v0.v[q] + g.w1*v1.v[q] + g.w2*v2.v[q] + g.w3*v3.v[q]);
            *reinterpret_cast<bf16x4*>(dst + k) = o;
        }
        if (lane == 0) wsB[m] = g.w0 + g.w1 + g.w2 + g.w3;
    } else if (blk < GATHER_BLKS + TRANS_BLKS) {
        const int tb = blk - GATHER_BLKS;          // 12x12 tiles of 64x64
        const int k0 = (tb % 12) * 64;
        const int n0 = (tb / 12) * 64;
        const int tx = t & 63, tyy = t >> 6;
        #pragma unroll
        for (int pass = 0; pass < 16; ++pass) {
            const int i = pass * 4 + tyy;
            T[i][tx] = (short)f2bf(Wv[(size_t)(k0 + i) * Dd + n0 + tx]);
        }
        __syncthreads();
        #pragma unroll
        for (int pass = 0; pass < 16; ++pass) {
            const int n = pass * 4 + tyy;
            WvT[(size_t)(n0 + n) * Dd + k0 + tx] = (unsigned short)T[tx][n];
        }
    } else {
        const int idx = (blk - GATHER_BLKS - TRANS_BLKS) * 256 + t;  // < 49152
        const int b = idx / Dd;
        const int d = idx - b * Dd;
        out[(size_t)b * Ss * Dd + d] = 1.0f;
    }
}

// ================= barrier-free MFMA GEMM: C = Ag @ WvT^T (+ wsum*bv) =================
// 128x128 tile, 4 waves (2x2 of 64x64), frags loaded straight from global (coalesced).
__global__ __launch_bounds__(256, 2) void gsa_gemm2(
    const unsigned short* __restrict__ Ag,    // (M,K)
    const unsigned short* __restrict__ WvT,   // (N,K)
    const float* __restrict__ wsB,
    const float* __restrict__ bv,
    float* __restrict__ out)
{
    const int t    = threadIdx.x;
    const int m0   = blockIdx.x * 128;
    const int n0   = blockIdx.y * 128;
    const int lane = t & 63;
    const int wv   = t >> 6;
    const int col  = lane & 15;
    const int quad = lane >> 4;
    const int wm   = (wv & 1) * 64;
    const int wn   = (wv >> 1) * 64;

    const unsigned short* ap[4];
    const unsigned short* bp[4];
    #pragma unroll
    for (int mi = 0; mi < 4; ++mi)
        ap[mi] = Ag + (size_t)(m0 + wm + mi * 16 + col) * Dd + quad * 8;
    #pragma unroll
    for (int ni = 0; ni < 4; ++ni)
        bp[ni] = WvT + (size_t)(n0 + wn + ni * 16 + col) * Dd + quad * 8;

    f32x4 acc[4][4];
    #pragma unroll
    for (int i = 0; i < 4; ++i)
        #pragma unroll
        for (int j = 0; j < 4; ++j) acc[i][j] = (f32x4)0.0f;

    bf16x8 aC[4], bC[4];
    #pragma unroll
    for (int mi = 0; mi < 4; ++mi) aC[mi] = *reinterpret_cast<const bf16x8*>(ap[mi]);
    #pragma unroll
    for (int ni = 0; ni < 4; ++ni) bC[ni] = *reinterpret_cast<const bf16x8*>(bp[ni]);

    #pragma unroll 2
    for (int kt = 32; kt <= Dd; kt += 32) {
        bf16x8 aN[4], bN[4];
        if (kt < Dd) {
            #pragma unroll
            for (int mi = 0; mi < 4; ++mi) aN[mi] = *reinterpret_cast<const bf16x8*>(ap[mi] + kt);
            #pragma unroll
            for (int ni = 0; ni < 4; ++ni) bN[ni] = *reinterpret_cast<const bf16x8*>(bp[ni] + kt);
        }
        #pragma unroll
        for (int mi = 0; mi < 4; ++mi)
            #pragma unroll
            for (int ni = 0; ni < 4; ++ni)
                acc[mi][ni] = __builtin_amdgcn_mfma_f32_16x16x32_bf16(
                    aC[mi], bC[ni], acc[mi][ni], 0, 0, 0);
        #pragma unroll
        for (int mi = 0; mi < 4; ++mi) aC[mi] = aN[mi];
        #pragma unroll
        for (int ni = 0; ni < 4; ++ni) bC[ni] = bN[ni];
    }

    float bvv[4];
    #pragma unroll
    for (int ni = 0; ni < 4; ++ni) bvv[ni] = bv[n0 + wn + ni * 16 + col];

    #pragma unroll
    for (int mi = 0; mi < 4; ++mi) {
        #pragma unroll
        for (int rg = 0; rg < 4; ++rg) {
            const int mg = m0 + wm + mi * 16 + quad * 4 + rg;  // C/D row = quad*4+reg
            const int b  = mg / Pp;
            const float wsv = wsB[mg];
            float* orow = out + ((size_t)(mg + b + 1)) * Dd;   // b*197 + 1 + p
            #pragma unroll
            for (int ni = 0; ni < 4; ++ni)
                orow[n0 + wn + ni * 16 + col] = acc[mi][ni][rg] + wsv * bvv[ni];
        }
    }
}

// ================= fallback: round-2 LDS MFMA path (ws >= 1.18MB only) =================
__global__ __launch_bounds__(256) void wv_transpose(
    const float* __restrict__ Wv, unsigned short* __restrict__ WvT)
{
    const int u = blockIdx.x * 256 + threadIdx.x;
    const int o = u * 8;
    const int n = o / Dd;
    const int k = o - n * Dd;
    bf16x8 tv;
    #pragma unroll
    for (int j = 0; j < 8; ++j) tv[j] = (short)f2bf(Wv[(size_t)(k + j) * Dd + n]);
    *reinterpret_cast<bf16x8*>(WvT + o) = tv;
}

__global__ __launch_bounds__(256) void gsa_fill_cls(float* __restrict__ out) {
    const int idx = blockIdx.x * 256 + threadIdx.x;
    if (idx < Bb * Dd) {
        const int b = idx / Dd;
        const int d = idx - b * Dd;
        out[(size_t)b * Ss * Dd + d] = 1.0f;
    }
}

__global__ __launch_bounds__(256, 2) void gsa_mfma(
    const float* __restrict__ x, const int* __restrict__ img_ids,
    const unsigned short* __restrict__ WvT, const float* __restrict__ bv,
    const float* __restrict__ avgs, const float* __restrict__ stds,
    const float* __restrict__ noise, float* __restrict__ out)
{
    __shared__ short As[128][40];
    __shared__ short Bs[128][40];
    __shared__ float wsums[128];
    const int t  = threadIdx.x;
    const int m0 = blockIdx.x * 128;
    const int n0 = blockIdx.y * 128;
    const int r  = t >> 1;
    const int kh = t & 1;
    const int ko = kh * 16;
    float w0, w1, w2, w3;
    const float *sA0, *sA1, *sA2, *sA3;
    {
        const int m = m0 + r, b = m / Pp, p = m - b * Pp;
        GParams g = gather_params(img_ids, avgs, stds, noise, b, p);
        w0 = g.w0; w1 = g.w1; w2 = g.w2; w3 = g.w3;
        const size_t xb = (size_t)b * Ss;
        sA0 = x + (xb + g.i0) * Dd + ko;
        sA1 = x + (xb + g.i1) * Dd + ko;
        sA2 = x + (xb + g.i2) * Dd + ko;
        sA3 = x + (xb + g.i3) * Dd + ko;
        if (kh == 0) wsums[r] = w0 + w1 + w2 + w3;
    }
    const unsigned short* srcB = WvT + (size_t)(n0 + r) * Dd + ko;
    const int lane = t & 63, wv = t >> 6;
    const int col = lane & 15, quad = lane >> 4;
    const int wm = (wv & 1) * 64, wn = (wv >> 1) * 64;
    const short* aptr[4];
    const short* bptr[4];
    #pragma unroll
    for (int mi = 0; mi < 4; ++mi) aptr[mi] = &As[wm + mi * 16 + col][quad * 8];
    #pragma unroll
    for (int ni = 0; ni < 4; ++ni) bptr[ni] = &Bs[wn + ni * 16 + col][quad * 8];
    f32x4 acc[4][4];
    #pragma unroll
    for (int i = 0; i < 4; ++i)
        #pragma unroll
        for (int j = 0; j < 4; ++j) acc[i][j] = (f32x4)0.0f;
    #pragma unroll 1
    for (int kt = 0; kt < Dd; kt += 32) {
        F4 l0[4], l1[4], l2[4], l3[4];
        #pragma unroll
        for (int c = 0; c < 4; ++c) {
            l0[c] = *reinterpret_cast<const F4*>(sA0 + kt + c * 4);
            l1[c] = *reinterpret_cast<const F4*>(sA1 + kt + c * 4);
            l2[c] = *reinterpret_cast<const F4*>(sA2 + kt + c * 4);
            l3[c] = *reinterpret_cast<const F4*>(sA3 + kt + c * 4);
        }
        bf16x8 b0 = *reinterpret_cast<const bf16x8*>(srcB + kt);
        bf16x8 b1 = *reinterpret_cast<const bf16x8*>(srcB + kt + 8);
        bf16x8 ua0, ua1;
        #pragma unroll
        for (int e = 0; e < 8; ++e) {
            const int c = e >> 2, q = e & 3;
            ua0[e] = (short)f2bf(w0*l0[c].v[q] + w1*l1[c].v[q] + w2*l2[c].v[q] + w3*l3[c].v[q]);
        }
        #pragma unroll
        for (int e = 0; e < 8; ++e) {
            const int c = (e + 8) >> 2, q = e & 3;
            ua1[e] = (short)f2bf(w0*l0[c].v[q] + w1*l1[c].v[q] + w2*l2[c].v[q] + w3*l3[c].v[q]);
        }
        __syncthreads();
        *reinterpret_cast<bf16x8*>(&As[r][ko])     = ua0;
        *reinterpret_cast<bf16x8*>(&As[r][ko + 8]) = ua1;
        *reinterpret_cast<bf16x8*>(&Bs[r][ko])     = b0;
        *reinterpret_cast<bf16x8*>(&Bs[r][ko + 8]) = b1;
        __syncthreads();
        bf16x8 aF[4], bF[4];
        #pragma unroll
        for (int mi = 0; mi < 4; ++mi) aF[mi] = *reinterpret_cast<const bf16x8*>(aptr[mi]);
        #pragma unroll
        for (int ni = 0; ni < 4; ++ni) bF[ni] = *reinterpret_cast<const bf16x8*>(bptr[ni]);
        #pragma unroll
        for (int mi = 0; mi < 4; ++mi)
            #pragma unroll
            for (int ni = 0; ni < 4; ++ni)
                acc[mi][ni] = __builtin_amdgcn_mfma_f32_16x16x32_bf16(
                    aF[mi], bF[ni], acc[mi][ni], 0, 0, 0);
    }
    float bvv[4];
    #pragma unroll
    for (int ni = 0; ni < 4; ++ni) bvv[ni] = bv[n0 + wn + ni * 16 + col];
    #pragma unroll
    for (int mi = 0; mi < 4; ++mi) {
        #pragma unroll
        for (int rg = 0; rg < 4; ++rg) {
            const int ml = wm + mi * 16 + quad * 4 + rg;
            const int mg = m0 + ml;
            const int b  = mg / Pp;
            const float wsv = wsums[ml];
            float* orow = out + ((size_t)(mg + b + 1)) * Dd;
            #pragma unroll
            for (int ni = 0; ni < 4; ++ni)
                orow[n0 + wn + ni * 16 + col] = acc[mi][ni][rg] + wsv * bvv[ni];
        }
    }
}

extern "C" void kernel_launch(void* const* d_in, const int* in_sizes, int n_in,
                              void* d_out, int out_size, void* d_ws, size_t ws_size,
                              hipStream_t stream) {
    // order: x, img_ids, mask, Wq, bq, Wk, bk, Wv, bv, avgs, std_devs, noise
    const float* x       = (const float*)d_in[0];
    const int*   img_ids = (const int*)  d_in[1];
    const float* Wv      = (const float*)d_in[7];
    const float* bv      = (const float*)d_in[8];
    const float* avgs    = (const float*)d_in[9];
    const float* stds    = (const float*)d_in[10];
    const float* noise   = (const float*)d_in[11];
    float* out = (float*)d_out;

    const size_t ag_bytes  = (size_t)Bb * Pp * Dd * sizeof(unsigned short); // 19.27 MB
    const size_t wvt_bytes = (size_t)Dd * Dd * sizeof(unsigned short);      // 1.18 MB
    const size_t ws_need   = ag_bytes + wvt_bytes + (size_t)Bb * Pp * sizeof(float);

    if (d_ws != nullptr && ws_size >= ws_need) {
        unsigned short* Ag  = (unsigned short*)d_ws;
        unsigned short* WvT = (unsigned short*)((char*)d_ws + ag_bytes);
        float*          wsB = (float*)((char*)d_ws + ag_bytes + wvt_bytes);
        gsa_prep<<<GATHER_BLKS + TRANS_BLKS + CLS_BLKS, 256, 0, stream>>>(
            x, img_ids, Wv, avgs, stds, noise, Ag, WvT, wsB, out);
        dim3 grid((Bb * Pp) / 128, Dd / 128);   // 98 x 6
        gsa_gemm2<<<grid, 256, 0, stream>>>(Ag, WvT, wsB, bv, out);
    } else {
        // fallback: round-2 path (needs only 1.18 MB)
        unsigned short* WvT = (unsigned short*)d_ws;
        gsa_fill_cls<<<(Bb * Dd + 255) / 256, 256, 0, stream>>>(out);
        wv_transpose<<<(Dd * Dd / 8) / 256, 256, 0, stream>>>(Wv, WvT);
        dim3 grid((Bb * Pp) / 128, Dd / 128);
        gsa_mfma<<<grid, 256, 0, stream>>>(x, img_ids, WvT, bv, avgs, stds, noise, out);
    }
}